// Round 10
// baseline (349.382 us; speedup 1.0000x reference)
//
#include <hip/hip_runtime.h>

#define N_NODES  100000
#define N_EDGES  3200000
#define NB       8                  // buckets
#define BN       12544              // nodes per bucket (8*12544 >= 100000)
#define PTHR     1024
#define NW       16                 // waves per partition block
#define PTILE    8192               // edges per partition tile
#define NTILES   ((N_EDGES + PTILE - 1) / PTILE)   // 391
#define CAP_TB   1280               // per-(tile,bucket) capacity (mean 1024, +8.5 sigma)
#define SENT     0xFFFFFFFFu
#define SA       32                 // acc blocks per bucket
#define GA       (NB * SA)          // 256
#define ATHR     1024
#define DTHR     1024
#define RTHR     512

// ws layout (4-byte words):
//  cnt[4096] | pedge[NTILES*NB*CAP_TB] | partials f32[GA*BN]
//  | dinv[N] | xs[N] | us[N] | uself[N]

// ---- K1: single-visit partition into per-(tile,bucket) fixed regions --------
__global__ __launch_bounds__(PTHR) void k_part(const int* __restrict__ src,
        const int* __restrict__ dstp, unsigned* __restrict__ cnt,
        unsigned* __restrict__ pedge) {
    __shared__ unsigned stage[PTILE];          // 32 KB
    __shared__ unsigned wcnt[NB * NW];         // bucket-major per-wave counts
    __shared__ unsigned woff[NB * NW];
    __shared__ unsigned bstart[NB + 1];
    const int tid = threadIdx.x, wave = tid >> 6, lane = tid & 63;
    const int qbeg = (blockIdx.x * PTILE) >> 2;
    int qend = qbeg + (PTILE >> 2);
    if (qend > (N_EDGES >> 2)) qend = N_EDGES >> 2;

    const uint4* s4 = (const uint4*)src;
    const uint4* d4 = (const uint4*)dstp;
    unsigned pk[8], pos[8];
    int bk[8];
    unsigned rc[NB];
    #pragma unroll
    for (int b = 0; b < NB; ++b) rc[b] = 0;

    #pragma unroll
    for (int k = 0; k < 2; ++k) {
        const int q = qbeg + k * PTHR + tid;
        const bool v = q < qend;
        uint4 sv = {0,0,0,0}, dv = {0,0,0,0};
        if (v) { sv = s4[q]; dv = d4[q]; }
        const unsigned ss[4] = { sv.x, sv.y, sv.z, sv.w };
        const unsigned dd[4] = { dv.x, dv.y, dv.z, dv.w };
        #pragma unroll
        for (int j = 0; j < 4; ++j) {
            const int i = k * 4 + j;
            const unsigned bb0 = dd[j] / BN;          // magic-mul
            const unsigned b = v ? bb0 : 0xFFu;
            bk[i] = v ? (int)b : -1;
            pk[i] = ss[j] | ((dd[j] - bb0 * BN) << 17);
            unsigned p = 0;
            #pragma unroll
            for (unsigned bb = 0; bb < NB; ++bb) {
                const unsigned long long m = __ballot(b == bb);
                if (b == bb)
                    p = rc[bb] + (unsigned)__popcll(m & ((1ull << lane) - 1ull));
                rc[bb] += (unsigned)__popcll(m);
            }
            pos[i] = p;
        }
    }
    #pragma unroll
    for (int b = 0; b < NB; ++b)
        if (lane == b) wcnt[b * NW + wave] = rc[b];
    __syncthreads();

    // exclusive scan over 128 bucket-major counters (wave 0, 2 elems/lane)
    if (wave == 0) {
        const int i0 = lane * 2, i1 = i0 + 1;
        unsigned a0 = wcnt[i0], a1 = wcnt[i1];
        unsigned ps = a0 + a1;
        #pragma unroll
        for (int d = 1; d < 64; d <<= 1) {
            unsigned o = __shfl_up(ps, d, 64);
            if (lane >= d) ps += o;
        }
        const unsigned excl = ps - (a0 + a1);
        woff[i0] = excl;
        woff[i1] = excl + a0;
        if (lane == 63) bstart[NB] = ps;
    }
    __syncthreads();
    if (tid < NB) bstart[tid] = woff[tid * NW];
    __syncthreads();

    // stage grouped by bucket
    #pragma unroll
    for (int i = 0; i < 8; ++i)
        if (bk[i] >= 0) stage[woff[bk[i] * NW + wave] + pos[i]] = pk[i];
    __syncthreads();

    // per-bucket copy-out to fixed region + sentinel padding
    for (int b = 0; b < NB; ++b) {
        const unsigned s0 = bstart[b];
        unsigned nb2 = bstart[b + 1] - s0;
        if (nb2 > CAP_TB) nb2 = CAP_TB;
        unsigned* dc = pedge + ((size_t)blockIdx.x * NB + b) * CAP_TB;
        for (unsigned j = tid; j < CAP_TB; j += PTHR)
            dc[j] = (j < nb2) ? stage[s0 + j] : SENT;
        if (tid == b) cnt[blockIdx.x * NB + b] = nb2;   // (diagnostic; unused)
    }
}

// ---- K2: per-bucket degree count -> dinv, xs (fused, 8 blocks) --------------
__global__ __launch_bounds__(DTHR) void k_deg(const unsigned* __restrict__ pedge,
        const float* __restrict__ x, float* __restrict__ dinv,
        float* __restrict__ xs) {
    __shared__ unsigned facc[BN];
    const int tid = threadIdx.x;
    const int bu = blockIdx.x;
    for (int i = tid; i < BN; i += DTHR) facc[i] = 0u;
    __syncthreads();
    // flat sweep over this bucket's NTILES regions
    const unsigned total = (unsigned)NTILES * CAP_TB;
    for (unsigned f = tid; f < total; f += DTHR) {
        const unsigned rl = f / CAP_TB;                // magic-mul
        const unsigned j  = f - rl * CAP_TB;
        const unsigned w = pedge[((size_t)rl * NB + bu) * CAP_TB + j];
        if (w != SENT) atomicAdd(&facc[w >> 17], 1u);
    }
    __syncthreads();
    for (int l = tid; l < BN; l += DTHR) {
        const int g = bu * BN + l;
        if (g < N_NODES) {
            const float di = rsqrtf((float)facc[l] + 1.f);   // + self loop
            dinv[g] = di;
            xs[g] = x[g] * di;
        }
    }
}

// ---- acc: scatter vals[src] into LDS bucket image ---------------------------
__global__ __launch_bounds__(ATHR) void k_acc(const unsigned* __restrict__ pedge,
        const float* __restrict__ vals, float* __restrict__ partials) {
    __shared__ float facc[BN];
    const int tid = threadIdx.x;
    const int bu = blockIdx.x / SA, sub = blockIdx.x % SA;
    for (int i = tid; i < BN; i += ATHR) facc[i] = 0.f;
    __syncthreads();
    const unsigned nt = ((unsigned)NTILES - sub + SA - 1) / SA;  // tiles for sub
    const unsigned total = nt * CAP_TB;
    for (unsigned f = tid; f < total; f += ATHR) {
        const unsigned rl = f / CAP_TB;
        const unsigned j  = f - rl * CAP_TB;
        const unsigned r  = sub + rl * SA;
        const unsigned w = pedge[((size_t)r * NB + bu) * CAP_TB + j];
        if (w != SENT) atomicAdd(&facc[w >> 17], vals[w & 0x1FFFFu]);
    }
    __syncthreads();
    float* po = partials + (size_t)blockIdx.x * BN;
    for (int i = tid; i < BN; i += ATHR) po[i] = facc[i];
}

// ---- partial reduction helper -----------------------------------------------
__device__ __forceinline__ float sum_partials(const float* __restrict__ partials,
                                              int g) {
    const int bu = g / BN, l = g - bu * BN;
    const float* pp = partials + (size_t)(bu * SA) * BN + l;
    float s = 0.f;
    #pragma unroll
    for (int k = 0; k < SA; ++k) s += pp[(size_t)k * BN];
    return s;
}

__global__ __launch_bounds__(RTHR) void k_red2(const float* __restrict__ x,
        const float* __restrict__ partials, const float* __restrict__ dinv,
        const float* __restrict__ W1, const float* __restrict__ b1,
        const float* __restrict__ W2, const float* __restrict__ Wl,
        float* __restrict__ us, float* __restrict__ uself) {
    const int g = blockIdx.x * RTHR + threadIdx.x;
    if (g >= N_NODES) return;
    const float sum = sum_partials(partials, g);
    const float di = dinv[g];
    const float s1 = di * sum + x[g] * di * di;
    float u = 0.f;
    #pragma unroll
    for (int c = 0; c < 16; ++c) {
        float vcc = 0.f;
        #pragma unroll
        for (int k = 0; k < 16; ++k) vcc += W2[c * 16 + k] * Wl[k];  // (W2@Wl)[c]
        u += fmaxf(W1[c] * s1 + b1[c], 0.f) * vcc;
    }
    us[g] = u * di;
    uself[g] = u * di * di;
}

__global__ __launch_bounds__(RTHR) void k_red3(const float* __restrict__ partials,
        const float* __restrict__ dinv, const float* __restrict__ uself,
        const float* __restrict__ W2, const float* __restrict__ b2,
        const float* __restrict__ Wl, const float* __restrict__ bl,
        float* __restrict__ out) {
    const int g = blockIdx.x * RTHR + threadIdx.x;
    if (g >= N_NODES) return;
    const float sum = sum_partials(partials, g);
    float vcb = bl[0];
    #pragma unroll
    for (int c = 0; c < 16; ++c) {
        float vcc = 0.f;
        #pragma unroll
        for (int k = 0; k < 16; ++k) vcc += W2[c * 16 + k] * Wl[k];
        vcb += b2[c] * vcc;
    }
    out[g] = dinv[g] * sum + uself[g] + vcb;
}

extern "C" void kernel_launch(void* const* d_in, const int* in_sizes, int n_in,
                              void* d_out, int out_size, void* d_ws, size_t ws_size,
                              hipStream_t stream) {
    const float* x  = (const float*)d_in[0];
    const int*   ei = (const int*)d_in[1];
    const float* W1 = (const float*)d_in[2];
    const float* b1 = (const float*)d_in[3];
    const float* W2 = (const float*)d_in[4];
    const float* b2 = (const float*)d_in[5];
    const float* Wl = (const float*)d_in[6];
    const float* bl = (const float*)d_in[7];
    float* out = (float*)d_out;

    const int* src  = ei;
    const int* dstp = ei + N_EDGES;

    unsigned* cnt      = (unsigned*)d_ws;                     // 4096 words
    unsigned* pedge    = cnt + 4096;
    float*    partials = (float*)(pedge + (size_t)NTILES * NB * CAP_TB);
    float*    dinv     = partials + (size_t)GA * BN;
    float*    xs       = dinv + N_NODES;
    float*    us       = xs + N_NODES;
    float*    uself    = us + N_NODES;

    const int red_blocks = (N_NODES + RTHR - 1) / RTHR;   // 196

    k_part<<<NTILES, PTHR, 0, stream>>>(src, dstp, cnt, pedge);
    k_deg<<<NB, DTHR, 0, stream>>>(pedge, x, dinv, xs);
    k_acc<<<GA, ATHR, 0, stream>>>(pedge, xs, partials);
    k_red2<<<red_blocks, RTHR, 0, stream>>>(x, partials, dinv, W1, b1, W2, Wl, us, uself);
    k_acc<<<GA, ATHR, 0, stream>>>(pedge, us, partials);
    k_red3<<<red_blocks, RTHR, 0, stream>>>(partials, dinv, uself, W2, b2, Wl, bl, out);
}

// Round 11
// 175.960 us; speedup vs baseline: 1.9856x; 1.9856x over previous
//
#include <hip/hip_runtime.h>

#define N_NODES  100000
#define N_EDGES  3200000
#define NB       8                  // buckets
#define BN       12544              // nodes per bucket (8*12544 >= 100000)
#define PTHR     1024
#define NW       16                 // waves per partition block
#define PTILE    8192               // edges per partition tile
#define NTILES   ((N_EDGES + PTILE - 1) / PTILE)   // 391
#define CAP_TB   1280               // per-(tile,bucket) capacity (mean 1024)
#define SENT     0xFFFFFFFFu
#define SA       32                 // acc blocks per bucket
#define GA       (NB * SA)          // 256
#define ATHR     1024
#define RTHR     512

// ws layout (4-byte words):
//  cnt[4096] | pedge[NTILES*NB*CAP_TB] | p16 (u16, GA*BN) | partials f32[GA*BN]
//  | dinv[N] | xs[N] | us[N] | uself[N]

// ---- K1: single-visit partition into per-(tile,bucket) fixed regions --------
__global__ __launch_bounds__(PTHR) void k_part(const int* __restrict__ src,
        const int* __restrict__ dstp, unsigned* __restrict__ cnt,
        unsigned* __restrict__ pedge) {
    __shared__ unsigned stage[PTILE];          // 32 KB
    __shared__ unsigned wcnt[NB * NW];         // bucket-major per-wave counts
    __shared__ unsigned woff[NB * NW];
    __shared__ unsigned bstart[NB + 1];
    const int tid = threadIdx.x, wave = tid >> 6, lane = tid & 63;
    const int qbeg = (blockIdx.x * PTILE) >> 2;
    int qend = qbeg + (PTILE >> 2);
    if (qend > (N_EDGES >> 2)) qend = N_EDGES >> 2;

    const uint4* s4 = (const uint4*)src;
    const uint4* d4 = (const uint4*)dstp;
    unsigned pk[8], pos[8];
    int bk[8];
    unsigned rc[NB];
    #pragma unroll
    for (int b = 0; b < NB; ++b) rc[b] = 0;

    #pragma unroll
    for (int k = 0; k < 2; ++k) {
        const int q = qbeg + k * PTHR + tid;
        const bool v = q < qend;
        uint4 sv = {0,0,0,0}, dv = {0,0,0,0};
        if (v) { sv = s4[q]; dv = d4[q]; }
        const unsigned ss[4] = { sv.x, sv.y, sv.z, sv.w };
        const unsigned dd[4] = { dv.x, dv.y, dv.z, dv.w };
        #pragma unroll
        for (int j = 0; j < 4; ++j) {
            const int i = k * 4 + j;
            const unsigned bb0 = dd[j] / BN;          // magic-mul
            const unsigned b = v ? bb0 : 0xFFu;
            bk[i] = v ? (int)b : -1;
            pk[i] = ss[j] | ((dd[j] - bb0 * BN) << 17);
            unsigned p = 0;
            #pragma unroll
            for (unsigned bb = 0; bb < NB; ++bb) {
                const unsigned long long m = __ballot(b == bb);
                if (b == bb)
                    p = rc[bb] + (unsigned)__popcll(m & ((1ull << lane) - 1ull));
                rc[bb] += (unsigned)__popcll(m);
            }
            pos[i] = p;
        }
    }
    #pragma unroll
    for (int b = 0; b < NB; ++b)
        if (lane == b) wcnt[b * NW + wave] = rc[b];
    __syncthreads();

    // exclusive scan over 128 bucket-major counters (wave 0, 2 elems/lane)
    if (wave == 0) {
        const int i0 = lane * 2, i1 = i0 + 1;
        unsigned a0 = wcnt[i0], a1 = wcnt[i1];
        unsigned ps = a0 + a1;
        #pragma unroll
        for (int d = 1; d < 64; d <<= 1) {
            unsigned o = __shfl_up(ps, d, 64);
            if (lane >= d) ps += o;
        }
        const unsigned excl = ps - (a0 + a1);
        woff[i0] = excl;
        woff[i1] = excl + a0;
        if (lane == 63) bstart[NB] = ps;
    }
    __syncthreads();
    if (tid < NB) bstart[tid] = woff[tid * NW];
    __syncthreads();

    // stage grouped by bucket
    #pragma unroll
    for (int i = 0; i < 8; ++i)
        if (bk[i] >= 0) stage[woff[bk[i] * NW + wave] + pos[i]] = pk[i];
    __syncthreads();

    // per-bucket copy-out to fixed region + sentinel padding
    for (int b = 0; b < NB; ++b) {
        const unsigned s0 = bstart[b];
        unsigned nb2 = bstart[b + 1] - s0;
        if (nb2 > CAP_TB) nb2 = CAP_TB;
        unsigned* dc = pedge + ((size_t)blockIdx.x * NB + b) * CAP_TB;
        for (unsigned j = tid; j < CAP_TB; j += PTHR)
            dc[j] = (j < nb2) ? stage[s0 + j] : SENT;
        if (tid == b) cnt[blockIdx.x * NB + b] = nb2;
    }
}

// ---- K2: degree accumulate (256 blocks) -> u16 partials ---------------------
__global__ __launch_bounds__(ATHR) void k_degacc(const unsigned* __restrict__ pedge,
        unsigned short* __restrict__ p16) {
    __shared__ unsigned facc[BN];
    const int tid = threadIdx.x;
    const int bu = blockIdx.x / SA, sub = blockIdx.x % SA;
    for (int i = tid; i < BN; i += ATHR) facc[i] = 0u;
    __syncthreads();
    const unsigned nt = ((unsigned)NTILES - sub + SA - 1) / SA;  // tiles for sub
    const unsigned total = nt * CAP_TB;
    for (unsigned f = tid; f < total; f += ATHR) {
        const unsigned rl = f / CAP_TB;
        const unsigned j  = f - rl * CAP_TB;
        const unsigned r  = sub + rl * SA;
        const unsigned w = pedge[((size_t)r * NB + bu) * CAP_TB + j];
        if (w != SENT) atomicAdd(&facc[w >> 17], 1u);
    }
    __syncthreads();
    unsigned short* po = p16 + (size_t)blockIdx.x * BN;
    for (int i = tid; i < BN; i += ATHR) po[i] = (unsigned short)facc[i];
}

// ---- red1: sum u16 degree partials -> dinv, xs ------------------------------
__global__ __launch_bounds__(RTHR) void k_red1(const float* __restrict__ x,
        const unsigned short* __restrict__ p16,
        float* __restrict__ dinv, float* __restrict__ xs) {
    const int g = blockIdx.x * RTHR + threadIdx.x;
    if (g >= N_NODES) return;
    const int bu = g / BN, l = g - bu * BN;
    const unsigned short* pp = p16 + (size_t)(bu * SA) * BN + l;
    unsigned run = 0;
    #pragma unroll
    for (int s = 0; s < SA; ++s) run += pp[(size_t)s * BN];
    const float di = rsqrtf((float)run + 1.f);      // + self loop
    dinv[g] = di;
    xs[g] = x[g] * di;
}

// ---- acc: scatter vals[src] into LDS bucket image ---------------------------
__global__ __launch_bounds__(ATHR) void k_acc(const unsigned* __restrict__ pedge,
        const float* __restrict__ vals, float* __restrict__ partials) {
    __shared__ float facc[BN];
    const int tid = threadIdx.x;
    const int bu = blockIdx.x / SA, sub = blockIdx.x % SA;
    for (int i = tid; i < BN; i += ATHR) facc[i] = 0.f;
    __syncthreads();
    const unsigned nt = ((unsigned)NTILES - sub + SA - 1) / SA;  // tiles for sub
    const unsigned total = nt * CAP_TB;
    for (unsigned f = tid; f < total; f += ATHR) {
        const unsigned rl = f / CAP_TB;
        const unsigned j  = f - rl * CAP_TB;
        const unsigned r  = sub + rl * SA;
        const unsigned w = pedge[((size_t)r * NB + bu) * CAP_TB + j];
        if (w != SENT) atomicAdd(&facc[w >> 17], vals[w & 0x1FFFFu]);
    }
    __syncthreads();
    float* po = partials + (size_t)blockIdx.x * BN;
    for (int i = tid; i < BN; i += ATHR) po[i] = facc[i];
}

// ---- partial reduction helper -----------------------------------------------
__device__ __forceinline__ float sum_partials(const float* __restrict__ partials,
                                              int g) {
    const int bu = g / BN, l = g - bu * BN;
    const float* pp = partials + (size_t)(bu * SA) * BN + l;
    float s = 0.f;
    #pragma unroll
    for (int k = 0; k < SA; ++k) s += pp[(size_t)k * BN];
    return s;
}

__global__ __launch_bounds__(RTHR) void k_red2(const float* __restrict__ x,
        const float* __restrict__ partials, const float* __restrict__ dinv,
        const float* __restrict__ W1, const float* __restrict__ b1,
        const float* __restrict__ W2, const float* __restrict__ Wl,
        float* __restrict__ us, float* __restrict__ uself) {
    const int g = blockIdx.x * RTHR + threadIdx.x;
    if (g >= N_NODES) return;
    const float sum = sum_partials(partials, g);
    const float di = dinv[g];
    const float s1 = di * sum + x[g] * di * di;
    float u = 0.f;
    #pragma unroll
    for (int c = 0; c < 16; ++c) {
        float vcc = 0.f;
        #pragma unroll
        for (int k = 0; k < 16; ++k) vcc += W2[c * 16 + k] * Wl[k];  // (W2@Wl)[c]
        u += fmaxf(W1[c] * s1 + b1[c], 0.f) * vcc;
    }
    us[g] = u * di;
    uself[g] = u * di * di;
}

__global__ __launch_bounds__(RTHR) void k_red3(const float* __restrict__ partials,
        const float* __restrict__ dinv, const float* __restrict__ uself,
        const float* __restrict__ W2, const float* __restrict__ b2,
        const float* __restrict__ Wl, const float* __restrict__ bl,
        float* __restrict__ out) {
    const int g = blockIdx.x * RTHR + threadIdx.x;
    if (g >= N_NODES) return;
    const float sum = sum_partials(partials, g);
    float vcb = bl[0];
    #pragma unroll
    for (int c = 0; c < 16; ++c) {
        float vcc = 0.f;
        #pragma unroll
        for (int k = 0; k < 16; ++k) vcc += W2[c * 16 + k] * Wl[k];
        vcb += b2[c] * vcc;
    }
    out[g] = dinv[g] * sum + uself[g] + vcb;
}

extern "C" void kernel_launch(void* const* d_in, const int* in_sizes, int n_in,
                              void* d_out, int out_size, void* d_ws, size_t ws_size,
                              hipStream_t stream) {
    const float* x  = (const float*)d_in[0];
    const int*   ei = (const int*)d_in[1];
    const float* W1 = (const float*)d_in[2];
    const float* b1 = (const float*)d_in[3];
    const float* W2 = (const float*)d_in[4];
    const float* b2 = (const float*)d_in[5];
    const float* Wl = (const float*)d_in[6];
    const float* bl = (const float*)d_in[7];
    float* out = (float*)d_out;

    const int* src  = ei;
    const int* dstp = ei + N_EDGES;

    unsigned* cnt       = (unsigned*)d_ws;                    // 4096 words
    unsigned* pedge     = cnt + 4096;
    unsigned short* p16 = (unsigned short*)(pedge + (size_t)NTILES * NB * CAP_TB);
    float*    partials  = (float*)(p16 + (size_t)GA * BN);
    float*    dinv      = partials + (size_t)GA * BN;
    float*    xs        = dinv + N_NODES;
    float*    us        = xs + N_NODES;
    float*    uself     = us + N_NODES;

    const int red_blocks = (N_NODES + RTHR - 1) / RTHR;   // 196

    k_part<<<NTILES, PTHR, 0, stream>>>(src, dstp, cnt, pedge);
    k_degacc<<<GA, ATHR, 0, stream>>>(pedge, p16);
    k_red1<<<red_blocks, RTHR, 0, stream>>>(x, p16, dinv, xs);
    k_acc<<<GA, ATHR, 0, stream>>>(pedge, xs, partials);
    k_red2<<<red_blocks, RTHR, 0, stream>>>(x, partials, dinv, W1, b1, W2, Wl, us, uself);
    k_acc<<<GA, ATHR, 0, stream>>>(pedge, us, partials);
    k_red3<<<red_blocks, RTHR, 0, stream>>>(partials, dinv, uself, W2, b2, Wl, bl, out);
}